// Round 1
// baseline (483.329 us; speedup 1.0000x reference)
//
#include <hip/hip_runtime.h>
#include <cstdint>

typedef __bf16 bf16;
typedef __bf16 bf16x8 __attribute__((ext_vector_type(8)));
typedef __bf16 bf16x4 __attribute__((ext_vector_type(4)));
typedef float f32x4 __attribute__((ext_vector_type(4)));

#define DIMN 2048
#define SEQ  2048
#define NH   16
#define HD   128

// -------- async global->LDS 16B helper (m97 pattern) --------
__device__ __forceinline__ void gld_lds16(const bf16* g, bf16* l) {
    __builtin_amdgcn_global_load_lds(
        (const __attribute__((address_space(1))) void*)g,
        (__attribute__((address_space(3))) void*)l,
        16, 0, 0);
}

// -------- fp32 -> bf16 cast (vectorized) --------
__global__ __launch_bounds__(256) void cast_f32_bf16(const float* __restrict__ src,
                                                     bf16* __restrict__ dst, int n4) {
    int i = blockIdx.x * 256 + threadIdx.x;
    if (i < n4) {
        float4 v = ((const float4*)src)[i];
        bf16x4 o;
        o[0] = (bf16)v.x; o[1] = (bf16)v.y; o[2] = (bf16)v.z; o[3] = (bf16)v.w;
        ((bf16x4*)dst)[i] = o;
    }
}

// -------- GEMM: C[m][n] = sum_k A[m][k]*B[n][k] + bias[n]  (A: Mx2048, B: 2048x2048 row-major = B^T form)
// 128x128 tile, BK=32, 256 threads = 4 waves, each wave 64x64 (4x4 of 16x16x32 MFMA).
template<int OUT_F32>
__global__ __launch_bounds__(256) void gemm_bt(
    const bf16* __restrict__ A,
    const bf16* __restrict__ Bw0, const bf16* __restrict__ Bw1, const bf16* __restrict__ Bw2,
    const float* __restrict__ bias0, const float* __restrict__ bias1, const float* __restrict__ bias2,
    void* __restrict__ C0, void* __restrict__ C1, void* __restrict__ C2)
{
    const int K = DIMN, N = DIMN;
    const bf16* Bw = Bw0; const float* bias = bias0; void* Cout = C0;
    if (blockIdx.z == 1) { Bw = Bw1; bias = bias1; Cout = C1; }
    if (blockIdx.z == 2) { Bw = Bw2; bias = bias2; Cout = C2; }

    __shared__ __attribute__((aligned(16))) bf16 As[128 * 32];
    __shared__ __attribute__((aligned(16))) bf16 Bs[128 * 32];

    const int t    = threadIdx.x;
    const int lane = t & 63, wave = t >> 6;
    const int l15  = lane & 15, quad = lane >> 4;
    const int wm   = (wave >> 1) * 64, wn = (wave & 1) * 64;
    const long bm  = (long)blockIdx.y * 128;
    const long bn  = (long)blockIdx.x * 128;

    // staging: thread t covers (row = t/4, 16B seg = t%4); pass2 = rows+64
    const int  srow = t >> 2;
    const int  scol = (t & 3) * 8;
    const bf16* ag0 = A  + (bm + srow) * (long)K + scol;
    const bf16* ag1 = A  + (bm + 64 + srow) * (long)K + scol;
    const bf16* bg0 = Bw + (bn + srow) * (long)K + scol;
    const bf16* bg1 = Bw + (bn + 64 + srow) * (long)K + scol;
    bf16* asd = As + t * 8;   // lane-contiguous LDS dest (row-major 128x32)
    bf16* bsd = Bs + t * 8;

    f32x4 acc[4][4] = {};

    for (int k0 = 0; k0 < K; k0 += 32) {
        gld_lds16(ag0 + k0, asd);
        gld_lds16(ag1 + k0, asd + 2048);
        gld_lds16(bg0 + k0, bsd);
        gld_lds16(bg1 + k0, bsd + 2048);
        __syncthreads();

        bf16x8 af[4], bfr[4];
#pragma unroll
        for (int i = 0; i < 4; i++)
            af[i] = *(const bf16x8*)(As + (wm + i * 16 + l15) * 32 + quad * 8);
#pragma unroll
        for (int j = 0; j < 4; j++)
            bfr[j] = *(const bf16x8*)(Bs + (wn + j * 16 + l15) * 32 + quad * 8);
#pragma unroll
        for (int i = 0; i < 4; i++)
#pragma unroll
            for (int j = 0; j < 4; j++)
                acc[i][j] = __builtin_amdgcn_mfma_f32_16x16x32_bf16(af[i], bfr[j], acc[i][j], 0, 0, 0);
        __syncthreads();
    }

    // epilogue: D row = quad*4+reg, col = l15 (m89-verified)
#pragma unroll
    for (int j = 0; j < 4; j++) {
        const long col = bn + wn + j * 16 + l15;
        const float bv = bias[col];
#pragma unroll
        for (int i = 0; i < 4; i++) {
            const long row0 = bm + wm + i * 16 + quad * 4;
#pragma unroll
            for (int r = 0; r < 4; r++) {
                float v = acc[i][j][r] + bv;
                if (OUT_F32) ((float*)Cout)[(row0 + r) * N + col] = v;
                else         ((bf16*)Cout)[(row0 + r) * N + col] = (bf16)v;
            }
        }
    }
}

// -------- fused RMSNorm + RoPE over a 2048-elem row, in-place bf16 --------
__global__ __launch_bounds__(256) void rmsnorm_rope(
    bf16* __restrict__ q, bf16* __restrict__ k,
    const float* __restrict__ gq, const float* __restrict__ gk,
    const float* __restrict__ freqs)
{
    const int row = blockIdx.x;                 // b*SEQ + s
    bf16* ptr = blockIdx.y ? k : q;
    const float* g = blockIdx.y ? gk : gq;
    const int s = row & (SEQ - 1);
    const int t = threadIdx.x;
    const int lane = t & 63, wave = t >> 6;

    bf16* base = ptr + (long)row * DIMN + t * 8;
    bf16x8 raw = *(const bf16x8*)base;
    float v[8]; float ss = 0.f;
#pragma unroll
    for (int j = 0; j < 8; j++) { v[j] = (float)raw[j]; ss += v[j] * v[j]; }
#pragma unroll
    for (int off = 32; off; off >>= 1) ss += __shfl_xor(ss, off, 64);
    __shared__ float red[4];
    if (lane == 0) red[wave] = ss;
    __syncthreads();
    float tot = red[0] + red[1] + red[2] + red[3];
    float rn = rsqrtf(tot * (1.0f / DIMN) + 1e-6f);

    const int e0 = t * 8;
    bf16x8 o;
#pragma unroll
    for (int pp = 0; pp < 4; pp++) {
        int e = e0 + pp * 2;
        float xr = v[pp * 2]     * rn * g[e];
        float xi = v[pp * 2 + 1] * rn * g[e + 1];
        int lc = (e >> 1) & 63;                  // pair index within head
        float cr = freqs[s * 128 + lc * 2];
        float ci = freqs[s * 128 + lc * 2 + 1];
        o[pp * 2]     = (bf16)(xr * cr - xi * ci);
        o[pp * 2 + 1] = (bf16)(xr * ci + xi * cr);
    }
    *(bf16x8*)base = o;
}

// -------- V transpose: vin[b*S+s][h*HD+d] -> vt[(b*NH+h)*HD+d][s] --------
__global__ __launch_bounds__(256) void transpose_v(const bf16* __restrict__ vin,
                                                   bf16* __restrict__ vt)
{
    __shared__ float tile[64][65];
    const int b = blockIdx.z, st = blockIdx.x, ct = blockIdx.y;
    const int tx = threadIdx.x & 63, ty = threadIdx.x >> 6;
#pragma unroll
    for (int ii = 0; ii < 16; ii++) {
        int r = ii * 4 + ty;
        tile[r][tx] = (float)vin[((long)(b * SEQ + st * 64 + r)) * DIMN + ct * 64 + tx];
    }
    __syncthreads();
#pragma unroll
    for (int ii = 0; ii < 16; ii++) {
        int c = ii * 4 + ty;
        vt[((long)(b * DIMN + ct * 64 + c)) * SEQ + st * 64 + tx] = (bf16)tile[tx][c];
    }
}

// -------- flash-style attention (no-max online softmax; softmax is shift-invariant,
// scores are O(+-10) so fp32 exp is safe). BM=128/block (32/wave), BN=64/iter.
__global__ __launch_bounds__(256, 2) void attention(
    const bf16* __restrict__ Q, const bf16* __restrict__ Kb,
    const bf16* __restrict__ Vt, bf16* __restrict__ O)
{
    // padded LDS rows (+8 elems) to break 16-way bank aliasing on b128 frag reads
    __shared__ __attribute__((aligned(16))) bf16 Ksh[64 * 136];      // [kr][d]  d=128 (+8)
    __shared__ __attribute__((aligned(16))) bf16 Vsh[128 * 72];      // [d][kr]  kr=64 (+8)
    __shared__ __attribute__((aligned(16))) bf16 Psh[4][32 * 72];    // per-wave P [m][kr]

    const int t = threadIdx.x;
    const int lane = t & 63, wave = t >> 6;
    const int l15 = lane & 15, quad = lane >> 4;
    const int bh = blockIdx.y, b = bh >> 4, h = bh & 15;
    const int qt = blockIdx.x;
    const long qrow0 = (long)b * SEQ + qt * 128 + wave * 32;
    const bf16* qbase = Q  + qrow0 * DIMN + h * HD;
    const bf16* kbase = Kb + (long)b * SEQ * DIMN + h * HD;
    const bf16* vbase = Vt + (long)bh * HD * SEQ;

    // Q fragments stay in registers for the whole kernel: A[m=l15][k=quad*8+j]
    bf16x8 qf[2][4];
#pragma unroll
    for (int i = 0; i < 2; i++)
#pragma unroll
        for (int kd = 0; kd < 4; kd++)
            qf[i][kd] = *(const bf16x8*)(qbase + (long)(i * 16 + l15) * DIMN + kd * 32 + quad * 8);

    f32x4 o_acc[2][8] = {};
    float L[2][4] = {};
    const float scale = 0.08838834764831845f;   // 1/sqrt(128)

    for (int kt = 0; kt < 32; kt++) {
        // ---- stage K (64x128) and Vt (128x64) tiles, padded rows ----
#pragma unroll
        for (int it = 0; it < 4; it++) {
            int fs = it * 256 + t;
            int kr = fs >> 4, ks = fs & 15;
            *(uint4*)(Ksh + kr * 136 + ks * 8) =
                *(const uint4*)(kbase + (long)(kt * 64 + kr) * DIMN + ks * 8);
            int dr = fs >> 3, vs = fs & 7;
            *(uint4*)(Vsh + dr * 72 + vs * 8) =
                *(const uint4*)(vbase + (long)dr * SEQ + kt * 64 + vs * 8);
        }
        __syncthreads();

        // ---- S = Q K^T ----
        f32x4 sc[2][4] = {};
#pragma unroll
        for (int j = 0; j < 4; j++)
#pragma unroll
            for (int kd = 0; kd < 4; kd++) {
                bf16x8 bfr = *(const bf16x8*)(Ksh + (j * 16 + l15) * 136 + kd * 32 + quad * 8);
                sc[0][j] = __builtin_amdgcn_mfma_f32_16x16x32_bf16(qf[0][kd], bfr, sc[0][j], 0, 0, 0);
                sc[1][j] = __builtin_amdgcn_mfma_f32_16x16x32_bf16(qf[1][kd], bfr, sc[1][j], 0, 0, 0);
            }

        // ---- exp, row-sum, P -> LDS (C-layout -> A-layout round trip) ----
#pragma unroll
        for (int i = 0; i < 2; i++) {
            float rsum[4] = {0.f, 0.f, 0.f, 0.f};
#pragma unroll
            for (int j = 0; j < 4; j++)
#pragma unroll
                for (int r = 0; r < 4; r++) {
                    float e = __expf(sc[i][j][r] * scale);
                    rsum[r] += e;
                    Psh[wave][(i * 16 + quad * 4 + r) * 72 + j * 16 + l15] = (bf16)e;
                }
#pragma unroll
            for (int r = 0; r < 4; r++) {
                float vv = rsum[r];
                vv += __shfl_xor(vv, 1, 64);
                vv += __shfl_xor(vv, 2, 64);
                vv += __shfl_xor(vv, 4, 64);
                vv += __shfl_xor(vv, 8, 64);
                L[i][r] += vv;
            }
        }
        __syncthreads();

        // ---- O += P V ----
#pragma unroll
        for (int kd = 0; kd < 2; kd++) {
            bf16x8 pa[2];
            pa[0] = *(const bf16x8*)(Psh[wave] + (l15)      * 72 + kd * 32 + quad * 8);
            pa[1] = *(const bf16x8*)(Psh[wave] + (16 + l15) * 72 + kd * 32 + quad * 8);
#pragma unroll
            for (int dj = 0; dj < 8; dj++) {
                bf16x8 vfr = *(const bf16x8*)(Vsh + (dj * 16 + l15) * 72 + kd * 32 + quad * 8);
                o_acc[0][dj] = __builtin_amdgcn_mfma_f32_16x16x32_bf16(pa[0], vfr, o_acc[0][dj], 0, 0, 0);
                o_acc[1][dj] = __builtin_amdgcn_mfma_f32_16x16x32_bf16(pa[1], vfr, o_acc[1][dj], 0, 0, 0);
            }
        }
        __syncthreads();
    }

    // ---- normalize + write (aliases Q buffer: each block writes only the
    // rows x cols it alone read, after all its Q reads drained at barrier 1) ----
#pragma unroll
    for (int i = 0; i < 2; i++)
#pragma unroll
        for (int r = 0; r < 4; r++) {
            float inv = 1.0f / L[i][r];
            long orow = qrow0 + i * 16 + quad * 4 + r;
#pragma unroll
            for (int dj = 0; dj < 8; dj++)
                O[orow * DIMN + h * HD + dj * 16 + l15] = (bf16)(o_acc[i][dj][r] * inv);
        }
}

extern "C" void kernel_launch(void* const* d_in, const int* in_sizes, int n_in,
                              void* d_out, int out_size, void* d_ws, size_t ws_size,
                              hipStream_t stream) {
    const float* x     = (const float*)d_in[0];
    const float* freqs = (const float*)d_in[1];
    const float* wq    = (const float*)d_in[2];
    const float* bq    = (const float*)d_in[3];
    const float* wk    = (const float*)d_in[4];
    const float* bk    = (const float*)d_in[5];
    const float* wv    = (const float*)d_in[6];
    const float* bv    = (const float*)d_in[7];
    const float* wo    = (const float*)d_in[8];
    const float* bo    = (const float*)d_in[9];
    const float* gq    = (const float*)d_in[10];
    const float* gk    = (const float*)d_in[11];
    float* out = (float*)d_out;

    const size_t MAT  = (size_t)4096 * 2048 * 2;   // 16 MiB (bf16 activations)
    const size_t WMAT = (size_t)2048 * 2048 * 2;   // 8 MiB  (bf16 weights)
    char* p = (char*)d_ws;
    bf16* xb  = (bf16*)p; p += MAT;
    bf16* wqb = (bf16*)p; p += WMAT;
    bf16* wkb = (bf16*)p; p += WMAT;
    bf16* wvb = (bf16*)p; p += WMAT;
    bf16* wob = (bf16*)p; p += WMAT;
    bf16* qb  = (bf16*)p; p += MAT;
    bf16* kb  = (bf16*)p; p += MAT;
    bf16* vb  = (bf16*)p; p += MAT;
    bf16* vt  = (bf16*)p; p += MAT;
    bf16* attn = qb;   // alias (safe, see attention kernel)

    // casts
    cast_f32_bf16<<<8192, 256, 0, stream>>>(x,  xb,  2097152);
    cast_f32_bf16<<<4096, 256, 0, stream>>>(wq, wqb, 1048576);
    cast_f32_bf16<<<4096, 256, 0, stream>>>(wk, wkb, 1048576);
    cast_f32_bf16<<<4096, 256, 0, stream>>>(wv, wvb, 1048576);
    cast_f32_bf16<<<4096, 256, 0, stream>>>(wo, wob, 1048576);

    // fused QKV projection (z selects weight set)
    gemm_bt<0><<<dim3(16, 32, 3), 256, 0, stream>>>(xb, wqb, wkb, wvb,
                                                    bq, bk, bv, qb, kb, vb);
    // rmsnorm + rope on q,k
    rmsnorm_rope<<<dim3(4096, 2), 256, 0, stream>>>(qb, kb, gq, gk, freqs);
    // transpose V for the PV B-operand
    transpose_v<<<dim3(32, 32, 2), 256, 0, stream>>>(vb, vt);
    // attention
    attention<<<dim3(16, 32), 256, 0, stream>>>(qb, kb, vt, attn);
    // output projection (fp32 out)
    gemm_bt<1><<<dim3(16, 32, 1), 256, 0, stream>>>(attn, wob, wob, wob,
                                                    bo, bo, bo, out, out, out);
}

// Round 2
// 469.297 us; speedup vs baseline: 1.0299x; 1.0299x over previous
//
#include <hip/hip_runtime.h>
#include <cstdint>

typedef __bf16 bf16;
typedef __bf16 bf16x8 __attribute__((ext_vector_type(8)));
typedef __bf16 bf16x4 __attribute__((ext_vector_type(4)));
typedef float f32x4 __attribute__((ext_vector_type(4)));

#define DIMN 2048
#define SEQ  2048
#define NH   16
#define HD   128

// -------- async global->LDS 16B helper (m97 pattern) --------
__device__ __forceinline__ void gld_lds16(const bf16* g, bf16* l) {
    __builtin_amdgcn_global_load_lds(
        (const __attribute__((address_space(1))) void*)g,
        (__attribute__((address_space(3))) void*)l,
        16, 0, 0);
}

// -------- fp32 -> bf16 cast, x (vectorized) --------
__global__ __launch_bounds__(256) void cast_f32_bf16(const float* __restrict__ src,
                                                     bf16* __restrict__ dst, int n4) {
    int i = blockIdx.x * 256 + threadIdx.x;
    if (i < n4) {
        float4 v = ((const float4*)src)[i];
        bf16x4 o;
        o[0] = (bf16)v.x; o[1] = (bf16)v.y; o[2] = (bf16)v.z; o[3] = (bf16)v.w;
        ((bf16x4*)dst)[i] = o;
    }
}

// -------- fused 4-weight cast (one launch instead of four) --------
__global__ __launch_bounds__(256) void cast_w4(
    const float* __restrict__ s0, const float* __restrict__ s1,
    const float* __restrict__ s2, const float* __restrict__ s3,
    bf16* __restrict__ d0, bf16* __restrict__ d1,
    bf16* __restrict__ d2, bf16* __restrict__ d3, int n4) {
    const float* src = s0; bf16* dst = d0;
    if (blockIdx.y == 1) { src = s1; dst = d1; }
    if (blockIdx.y == 2) { src = s2; dst = d2; }
    if (blockIdx.y == 3) { src = s3; dst = d3; }
    int i = blockIdx.x * 256 + threadIdx.x;
    if (i < n4) {
        float4 v = ((const float4*)src)[i];
        bf16x4 o;
        o[0] = (bf16)v.x; o[1] = (bf16)v.y; o[2] = (bf16)v.z; o[3] = (bf16)v.w;
        ((bf16x4*)dst)[i] = o;
    }
}

// -------- GEMM: C[m][n] = sum_k A[m][k]*B[n][k] + bias[n]
// 128x128 tile, BK=32, 4 waves, 64x64/wave (4x4 of 16x16x32 MFMA).
// LDS layout XOR-swizzled: LDS(row, seg) holds global seg (seg ^ ((row>>1)&3)).
// Fragment reads then hit 8 distinct 4-bank groups x2 lanes = conflict-free.
template<int OUT_F32>
__global__ __launch_bounds__(256) void gemm_bt(
    const bf16* __restrict__ A,
    const bf16* __restrict__ Bw0, const bf16* __restrict__ Bw1, const bf16* __restrict__ Bw2,
    const float* __restrict__ bias0, const float* __restrict__ bias1, const float* __restrict__ bias2,
    void* __restrict__ C0, void* __restrict__ C1, void* __restrict__ C2)
{
    const int K = DIMN, N = DIMN;
    const bf16* Bw = Bw0; const float* bias = bias0; void* Cout = C0;
    if (blockIdx.z == 1) { Bw = Bw1; bias = bias1; Cout = C1; }
    if (blockIdx.z == 2) { Bw = Bw2; bias = bias2; Cout = C2; }

    __shared__ __attribute__((aligned(16))) bf16 As[128 * 32];
    __shared__ __attribute__((aligned(16))) bf16 Bs[128 * 32];

    const int t    = threadIdx.x;
    const int lane = t & 63, wave = t >> 6;
    const int l15  = lane & 15, quad = lane >> 4;
    const int wm   = (wave >> 1) * 64, wn = (wave & 1) * 64;
    const long bm  = (long)blockIdx.y * 128;
    const long bn  = (long)blockIdx.x * 128;

    // staging: thread t covers (row = t/4); global 16B-seg is XOR-swizzled so the
    // lane-contiguous LDS dest yields the swizzled layout. (row+64 has same key.)
    const int  srow = t >> 2;
    const int  sseg = (t & 3) ^ ((srow >> 1) & 3);
    const int  scol = sseg * 8;
    const bf16* ag0 = A  + (bm + srow) * (long)K + scol;
    const bf16* ag1 = A  + (bm + 64 + srow) * (long)K + scol;
    const bf16* bg0 = Bw + (bn + srow) * (long)K + scol;
    const bf16* bg1 = Bw + (bn + 64 + srow) * (long)K + scol;
    bf16* asd = As + t * 8;
    bf16* bsd = Bs + t * 8;

    // frag-read swizzle: seg = quad ^ ((row>>1)&3); row>>1&3 == (l15>>1)&3 here
    const int sw = (quad ^ ((l15 >> 1) & 3)) * 8;

    f32x4 acc[4][4] = {};

    for (int k0 = 0; k0 < K; k0 += 32) {
        gld_lds16(ag0 + k0, asd);
        gld_lds16(ag1 + k0, asd + 2048);
        gld_lds16(bg0 + k0, bsd);
        gld_lds16(bg1 + k0, bsd + 2048);
        __syncthreads();

        bf16x8 af[4], bfr[4];
#pragma unroll
        for (int i = 0; i < 4; i++)
            af[i] = *(const bf16x8*)(As + (wm + i * 16 + l15) * 32 + sw);
#pragma unroll
        for (int j = 0; j < 4; j++)
            bfr[j] = *(const bf16x8*)(Bs + (wn + j * 16 + l15) * 32 + sw);
#pragma unroll
        for (int i = 0; i < 4; i++)
#pragma unroll
            for (int j = 0; j < 4; j++)
                acc[i][j] = __builtin_amdgcn_mfma_f32_16x16x32_bf16(af[i], bfr[j], acc[i][j], 0, 0, 0);
        __syncthreads();
    }

    // epilogue: D row = quad*4+reg, col = l15 (m89-verified)
#pragma unroll
    for (int j = 0; j < 4; j++) {
        const long col = bn + wn + j * 16 + l15;
        const float bv = bias[col];
#pragma unroll
        for (int i = 0; i < 4; i++) {
            const long row0 = bm + wm + i * 16 + quad * 4;
#pragma unroll
            for (int r = 0; r < 4; r++) {
                float v = acc[i][j][r] + bv;
                if (OUT_F32) ((float*)Cout)[(row0 + r) * N + col] = v;
                else         ((bf16*)Cout)[(row0 + r) * N + col] = (bf16)v;
            }
        }
    }
}

// -------- fused RMSNorm + RoPE over a 2048-elem row, in-place bf16 --------
__global__ __launch_bounds__(256) void rmsnorm_rope(
    bf16* __restrict__ q, bf16* __restrict__ k,
    const float* __restrict__ gq, const float* __restrict__ gk,
    const float* __restrict__ freqs)
{
    const int row = blockIdx.x;                 // b*SEQ + s
    bf16* ptr = blockIdx.y ? k : q;
    const float* g = blockIdx.y ? gk : gq;
    const int s = row & (SEQ - 1);
    const int t = threadIdx.x;
    const int lane = t & 63, wave = t >> 6;

    bf16* base = ptr + (long)row * DIMN + t * 8;
    bf16x8 raw = *(const bf16x8*)base;
    float v[8]; float ss = 0.f;
#pragma unroll
    for (int j = 0; j < 8; j++) { v[j] = (float)raw[j]; ss += v[j] * v[j]; }
#pragma unroll
    for (int off = 32; off; off >>= 1) ss += __shfl_xor(ss, off, 64);
    __shared__ float red[4];
    if (lane == 0) red[wave] = ss;
    __syncthreads();
    float tot = red[0] + red[1] + red[2] + red[3];
    float rn = rsqrtf(tot * (1.0f / DIMN) + 1e-6f);

    const int e0 = t * 8;
    bf16x8 o;
#pragma unroll
    for (int pp = 0; pp < 4; pp++) {
        int e = e0 + pp * 2;
        float xr = v[pp * 2]     * rn * g[e];
        float xi = v[pp * 2 + 1] * rn * g[e + 1];
        int lc = (e >> 1) & 63;                  // pair index within head
        float cr = freqs[s * 128 + lc * 2];
        float ci = freqs[s * 128 + lc * 2 + 1];
        o[pp * 2]     = (bf16)(xr * cr - xi * ci);
        o[pp * 2 + 1] = (bf16)(xr * ci + xi * cr);
    }
    *(bf16x8*)base = o;
}

// -------- V transpose: vin[b*S+s][h*HD+d] -> vt[(b*NH+h)*HD+d][s] --------
__global__ __launch_bounds__(256) void transpose_v(const bf16* __restrict__ vin,
                                                   bf16* __restrict__ vt)
{
    __shared__ float tile[64][65];
    const int b = blockIdx.z, st = blockIdx.x, ct = blockIdx.y;
    const int tx = threadIdx.x & 63, ty = threadIdx.x >> 6;
#pragma unroll
    for (int ii = 0; ii < 16; ii++) {
        int r = ii * 4 + ty;
        tile[r][tx] = (float)vin[((long)(b * SEQ + st * 64 + r)) * DIMN + ct * 64 + tx];
    }
    __syncthreads();
#pragma unroll
    for (int ii = 0; ii < 16; ii++) {
        int c = ii * 4 + ty;
        vt[((long)(b * DIMN + ct * 64 + c)) * SEQ + st * 64 + tx] = (bf16)tile[tx][c];
    }
}

// -------- flash-style attention (no-max softmax: shift-invariant, scores O(+-10),
// fp32 exp safe). BM=128/block (32/wave), BN=64/iter.
__global__ __launch_bounds__(256, 2) void attention(
    const bf16* __restrict__ Q, const bf16* __restrict__ Kb,
    const bf16* __restrict__ Vt, bf16* __restrict__ O)
{
    // K/V padded rows (odd 16B-seg stride -> conflict-free b128 reads)
    __shared__ __attribute__((aligned(16))) bf16 Ksh[64 * 136];      // [kr][d]
    __shared__ __attribute__((aligned(16))) bf16 Vsh[128 * 72];      // [d][kr]
    __shared__ __attribute__((aligned(16))) bf16 Psh[4][32 * 72];    // per-wave P [m][kr], seg-swizzled

    const int t = threadIdx.x;
    const int lane = t & 63, wave = t >> 6;
    const int l15 = lane & 15, quad = lane >> 4;
    const int bh = blockIdx.y, b = bh >> 4, h = bh & 15;
    const int qt = blockIdx.x;
    const long qrow0 = (long)b * SEQ + qt * 128 + wave * 32;
    const bf16* qbase = Q  + qrow0 * DIMN + h * HD;
    const bf16* kbase = Kb + (long)b * SEQ * DIMN + h * HD;
    const bf16* vbase = Vt + (long)bh * HD * SEQ;

    // Q fragments stay in registers: A[m=l15][k=quad*8+j]
    bf16x8 qf[2][4];
#pragma unroll
    for (int i = 0; i < 2; i++)
#pragma unroll
        for (int kd = 0; kd < 4; kd++)
            qf[i][kd] = *(const bf16x8*)(qbase + (long)(i * 16 + l15) * DIMN + kd * 32 + quad * 8);

    f32x4 o_acc[2][8] = {};
    float L[2][4] = {};
    const float scale = 0.08838834764831845f;   // 1/sqrt(128)
    const int rkey = (l15 >> 2) & 3;            // P read-side swizzle key

    for (int kt = 0; kt < 32; kt++) {
        // ---- stage K (64x128) and Vt (128x64) tiles ----
#pragma unroll
        for (int it = 0; it < 4; it++) {
            int fs = it * 256 + t;
            int kr = fs >> 4, ks = fs & 15;
            *(uint4*)(Ksh + kr * 136 + ks * 8) =
                *(const uint4*)(kbase + (long)(kt * 64 + kr) * DIMN + ks * 8);
            int dr = fs >> 3, vs = fs & 7;
            *(uint4*)(Vsh + dr * 72 + vs * 8) =
                *(const uint4*)(vbase + (long)dr * SEQ + kt * 64 + vs * 8);
        }
        __syncthreads();

        // ---- S = Q K^T ----
        f32x4 sc[2][4] = {};
#pragma unroll
        for (int j = 0; j < 4; j++)
#pragma unroll
            for (int kd = 0; kd < 4; kd++) {
                bf16x8 bfr = *(const bf16x8*)(Ksh + (j * 16 + l15) * 136 + kd * 32 + quad * 8);
                sc[0][j] = __builtin_amdgcn_mfma_f32_16x16x32_bf16(qf[0][kd], bfr, sc[0][j], 0, 0, 0);
                sc[1][j] = __builtin_amdgcn_mfma_f32_16x16x32_bf16(qf[1][kd], bfr, sc[1][j], 0, 0, 0);
            }

        // ---- exp, row-sum, P -> LDS (C-layout -> A-layout; seg-XOR on write:
        // write key = (row>>2)&3 == quad, spreads quad pairs across bank groups) ----
#pragma unroll
        for (int i = 0; i < 2; i++) {
            float rsum[4] = {0.f, 0.f, 0.f, 0.f};
#pragma unroll
            for (int j = 0; j < 4; j++) {
                const int seg = 2 * j + (l15 >> 3);
                const int segS = seg ^ quad;
#pragma unroll
                for (int r = 0; r < 4; r++) {
                    float e = __expf(sc[i][j][r] * scale);
                    rsum[r] += e;
                    Psh[wave][(i * 16 + quad * 4 + r) * 72 + segS * 8 + (l15 & 7)] = (bf16)e;
                }
            }
#pragma unroll
            for (int r = 0; r < 4; r++) {
                float vv = rsum[r];
                vv += __shfl_xor(vv, 1, 64);
                vv += __shfl_xor(vv, 2, 64);
                vv += __shfl_xor(vv, 4, 64);
                vv += __shfl_xor(vv, 8, 64);
                L[i][r] += vv;
            }
        }
        // NOTE: no barrier here — Psh[wave] is wave-private, LDS ops are in-order per wave.

        // ---- O += P V ----
#pragma unroll
        for (int kd = 0; kd < 2; kd++) {
            bf16x8 pa[2];
            pa[0] = *(const bf16x8*)(Psh[wave] + (l15)      * 72 + ((kd * 4 + quad) ^ rkey) * 8);
            pa[1] = *(const bf16x8*)(Psh[wave] + (16 + l15) * 72 + ((kd * 4 + quad) ^ rkey) * 8);
#pragma unroll
            for (int dj = 0; dj < 8; dj++) {
                bf16x8 vfr = *(const bf16x8*)(Vsh + (dj * 16 + l15) * 72 + kd * 32 + quad * 8);
                o_acc[0][dj] = __builtin_amdgcn_mfma_f32_16x16x32_bf16(pa[0], vfr, o_acc[0][dj], 0, 0, 0);
                o_acc[1][dj] = __builtin_amdgcn_mfma_f32_16x16x32_bf16(pa[1], vfr, o_acc[1][dj], 0, 0, 0);
            }
        }
        __syncthreads();
    }

    // ---- normalize + write (aliases Q buffer: safe, see round-0 note) ----
#pragma unroll
    for (int i = 0; i < 2; i++)
#pragma unroll
        for (int r = 0; r < 4; r++) {
            float inv = 1.0f / L[i][r];
            long orow = qrow0 + i * 16 + quad * 4 + r;
#pragma unroll
            for (int dj = 0; dj < 8; dj++)
                O[orow * DIMN + h * HD + dj * 16 + l15] = (bf16)(o_acc[i][dj][r] * inv);
        }
}

extern "C" void kernel_launch(void* const* d_in, const int* in_sizes, int n_in,
                              void* d_out, int out_size, void* d_ws, size_t ws_size,
                              hipStream_t stream) {
    const float* x     = (const float*)d_in[0];
    const float* freqs = (const float*)d_in[1];
    const float* wq    = (const float*)d_in[2];
    const float* bq    = (const float*)d_in[3];
    const float* wk    = (const float*)d_in[4];
    const float* bk    = (const float*)d_in[5];
    const float* wv    = (const float*)d_in[6];
    const float* bv    = (const float*)d_in[7];
    const float* wo    = (const float*)d_in[8];
    const float* bo    = (const float*)d_in[9];
    const float* gq    = (const float*)d_in[10];
    const float* gk    = (const float*)d_in[11];
    float* out = (float*)d_out;

    const size_t MAT  = (size_t)4096 * 2048 * 2;   // 16 MiB (bf16 activations)
    const size_t WMAT = (size_t)2048 * 2048 * 2;   // 8 MiB  (bf16 weights)
    char* p = (char*)d_ws;
    bf16* xb  = (bf16*)p; p += MAT;
    bf16* wqb = (bf16*)p; p += WMAT;
    bf16* wkb = (bf16*)p; p += WMAT;
    bf16* wvb = (bf16*)p; p += WMAT;
    bf16* wob = (bf16*)p; p += WMAT;
    bf16* qb  = (bf16*)p; p += MAT;
    bf16* kb  = (bf16*)p; p += MAT;
    bf16* vb  = (bf16*)p; p += MAT;
    bf16* vt  = (bf16*)p; p += MAT;
    bf16* attn = qb;   // alias (safe, see attention kernel)

    // casts (x + fused 4-weight)
    cast_f32_bf16<<<8192, 256, 0, stream>>>(x, xb, 2097152);
    cast_w4<<<dim3(4096, 4), 256, 0, stream>>>(wq, wk, wv, wo, wqb, wkb, wvb, wob, 1048576);

    // fused QKV projection (z selects weight set)
    gemm_bt<0><<<dim3(16, 32, 3), 256, 0, stream>>>(xb, wqb, wkb, wvb,
                                                    bq, bk, bv, qb, kb, vb);
    // rmsnorm + rope on q,k
    rmsnorm_rope<<<dim3(4096, 2), 256, 0, stream>>>(qb, kb, gq, gk, freqs);
    // transpose V for the PV B-operand
    transpose_v<<<dim3(32, 32, 2), 256, 0, stream>>>(vb, vt);
    // attention
    attention<<<dim3(16, 32), 256, 0, stream>>>(qb, kb, vt, attn);
    // output projection (fp32 out)
    gemm_bt<1><<<dim3(16, 32, 1), 256, 0, stream>>>(attn, wob, wob, wob,
                                                    bo, bo, bo, out, out, out);
}

// Round 3
// 411.141 us; speedup vs baseline: 1.1756x; 1.1414x over previous
//
#include <hip/hip_runtime.h>
#include <cstdint>

typedef __bf16 bf16;
typedef __bf16 bf16x8 __attribute__((ext_vector_type(8)));
typedef __bf16 bf16x4 __attribute__((ext_vector_type(4)));
typedef float f32x4 __attribute__((ext_vector_type(4)));

#define DIMN 2048
#define SEQ  2048
#define NH   16
#define HD   128

// -------- async global->LDS 16B helper (m97 pattern) --------
__device__ __forceinline__ void gld_lds16(const bf16* g, bf16* l) {
    __builtin_amdgcn_global_load_lds(
        (const __attribute__((address_space(1))) void*)g,
        (__attribute__((address_space(3))) void*)l,
        16, 0, 0);
}

// -------- fp32 -> bf16 cast, x (vectorized) --------
__global__ __launch_bounds__(256) void cast_f32_bf16(const float* __restrict__ src,
                                                     bf16* __restrict__ dst, int n4) {
    int i = blockIdx.x * 256 + threadIdx.x;
    if (i < n4) {
        float4 v = ((const float4*)src)[i];
        bf16x4 o;
        o[0] = (bf16)v.x; o[1] = (bf16)v.y; o[2] = (bf16)v.z; o[3] = (bf16)v.w;
        ((bf16x4*)dst)[i] = o;
    }
}

// -------- fused 4-weight cast --------
__global__ __launch_bounds__(256) void cast_w4(
    const float* __restrict__ s0, const float* __restrict__ s1,
    const float* __restrict__ s2, const float* __restrict__ s3,
    bf16* __restrict__ d0, bf16* __restrict__ d1,
    bf16* __restrict__ d2, bf16* __restrict__ d3, int n4) {
    const float* src = s0; bf16* dst = d0;
    if (blockIdx.y == 1) { src = s1; dst = d1; }
    if (blockIdx.y == 2) { src = s2; dst = d2; }
    if (blockIdx.y == 3) { src = s3; dst = d3; }
    int i = blockIdx.x * 256 + threadIdx.x;
    if (i < n4) {
        float4 v = ((const float4*)src)[i];
        bf16x4 o;
        o[0] = (bf16)v.x; o[1] = (bf16)v.y; o[2] = (bf16)v.z; o[3] = (bf16)v.w;
        ((bf16x4*)dst)[i] = o;
    }
}

// -------- GEMM: C[m][n] = sum_k A[m][k]*B[n][k] + bias[n]
// 128x128 tile, BK=64 (32 MFMA/barrier, halves barrier-drain count vs BK=32).
// LDS rows 128B; seg-XOR swizzle p = seg ^ (row&7) -> conflict-free b128 reads.
template<int OUT_F32>
__global__ __launch_bounds__(256) void gemm_bt(
    const bf16* __restrict__ A,
    const bf16* __restrict__ Bw0, const bf16* __restrict__ Bw1, const bf16* __restrict__ Bw2,
    const float* __restrict__ bias0, const float* __restrict__ bias1, const float* __restrict__ bias2,
    void* __restrict__ C0, void* __restrict__ C1, void* __restrict__ C2)
{
    const int K = DIMN, N = DIMN;
    const bf16* Bw = Bw0; const float* bias = bias0; void* Cout = C0;
    if (blockIdx.z == 1) { Bw = Bw1; bias = bias1; Cout = C1; }
    if (blockIdx.z == 2) { Bw = Bw2; bias = bias2; Cout = C2; }

    __shared__ __attribute__((aligned(16))) bf16 As[128 * 64];
    __shared__ __attribute__((aligned(16))) bf16 Bs[128 * 64];

    const int t    = threadIdx.x;
    const int lane = t & 63, wave = t >> 6;
    const int l15  = lane & 15, quad = lane >> 4;
    const int wm   = (wave >> 1) * 64, wn = (wave & 1) * 64;
    const long bm  = (long)blockIdx.y * 128;
    const long bn  = (long)blockIdx.x * 128;

    // staging: 4 passes x 256 threads cover 128 rows x 8 segs; global seg XOR'd
    const bf16* agp[4]; const bf16* bgp[4]; bf16* asd[4]; bf16* bsd[4];
#pragma unroll
    for (int it = 0; it < 4; it++) {
        int fs  = it * 256 + t;
        int row = fs >> 3;
        int gs  = (fs & 7) ^ (row & 7);
        agp[it] = A  + (bm + row) * (long)K + gs * 8;
        bgp[it] = Bw + (bn + row) * (long)K + gs * 8;
        asd[it] = As + fs * 8;
        bsd[it] = Bs + fs * 8;
    }
    const int swl = l15 & 7;   // frag-read swizzle key

    f32x4 acc[4][4] = {};

    for (int k0 = 0; k0 < K; k0 += 64) {
#pragma unroll
        for (int it = 0; it < 4; it++) {
            gld_lds16(agp[it] + k0, asd[it]);
            gld_lds16(bgp[it] + k0, bsd[it]);
        }
        __syncthreads();

#pragma unroll
        for (int ks2 = 0; ks2 < 2; ks2++) {
            const int sw = ((ks2 * 4 + quad) ^ swl) * 8;
            bf16x8 af[4], bfr[4];
#pragma unroll
            for (int i = 0; i < 4; i++)
                af[i] = *(const bf16x8*)(As + (wm + i * 16 + l15) * 64 + sw);
#pragma unroll
            for (int j = 0; j < 4; j++)
                bfr[j] = *(const bf16x8*)(Bs + (wn + j * 16 + l15) * 64 + sw);
#pragma unroll
            for (int i = 0; i < 4; i++)
#pragma unroll
                for (int j = 0; j < 4; j++)
                    acc[i][j] = __builtin_amdgcn_mfma_f32_16x16x32_bf16(af[i], bfr[j], acc[i][j], 0, 0, 0);
        }
        __syncthreads();
    }

    // epilogue: D row = quad*4+reg, col = l15 (m89-verified)
#pragma unroll
    for (int j = 0; j < 4; j++) {
        const long col = bn + wn + j * 16 + l15;
        const float bv = bias[col];
#pragma unroll
        for (int i = 0; i < 4; i++) {
            const long row0 = bm + wm + i * 16 + quad * 4;
#pragma unroll
            for (int r = 0; r < 4; r++) {
                float v = acc[i][j][r] + bv;
                if (OUT_F32) ((float*)Cout)[(row0 + r) * N + col] = v;
                else         ((bf16*)Cout)[(row0 + r) * N + col] = (bf16)v;
            }
        }
    }
}

// -------- fused RMSNorm + RoPE; Q additionally pre-scaled by 1/sqrt(HD) --------
__global__ __launch_bounds__(256) void rmsnorm_rope(
    bf16* __restrict__ q, bf16* __restrict__ k,
    const float* __restrict__ gq, const float* __restrict__ gk,
    const float* __restrict__ freqs)
{
    const int row = blockIdx.x;                 // b*SEQ + s
    bf16* ptr = blockIdx.y ? k : q;
    const float* g = blockIdx.y ? gk : gq;
    const float osc = blockIdx.y ? 1.0f : 0.08838834764831845f;  // fold attn scale into Q
    const int s = row & (SEQ - 1);
    const int t = threadIdx.x;
    const int lane = t & 63, wave = t >> 6;

    bf16* base = ptr + (long)row * DIMN + t * 8;
    bf16x8 raw = *(const bf16x8*)base;
    float v[8]; float ss = 0.f;
#pragma unroll
    for (int j = 0; j < 8; j++) { v[j] = (float)raw[j]; ss += v[j] * v[j]; }
#pragma unroll
    for (int off = 32; off; off >>= 1) ss += __shfl_xor(ss, off, 64);
    __shared__ float red[4];
    if (lane == 0) red[wave] = ss;
    __syncthreads();
    float tot = red[0] + red[1] + red[2] + red[3];
    float rn = rsqrtf(tot * (1.0f / DIMN) + 1e-6f);

    const int e0 = t * 8;
    bf16x8 o;
#pragma unroll
    for (int pp = 0; pp < 4; pp++) {
        int e = e0 + pp * 2;
        float xr = v[pp * 2]     * rn * g[e];
        float xi = v[pp * 2 + 1] * rn * g[e + 1];
        int lc = (e >> 1) & 63;                  // pair index within head
        float cr = freqs[s * 128 + lc * 2];
        float ci = freqs[s * 128 + lc * 2 + 1];
        o[pp * 2]     = (bf16)((xr * cr - xi * ci) * osc);
        o[pp * 2 + 1] = (bf16)((xr * ci + xi * cr) * osc);
    }
    *(bf16x8*)base = o;
}

// -------- V transpose: vin[b*S+s][h*HD+d] -> vt[(b*NH+h)*HD+d][s] --------
__global__ __launch_bounds__(256) void transpose_v(const bf16* __restrict__ vin,
                                                   bf16* __restrict__ vt)
{
    __shared__ float tile[64][65];
    const int b = blockIdx.z, st = blockIdx.x, ct = blockIdx.y;
    const int tx = threadIdx.x & 63, ty = threadIdx.x >> 6;
#pragma unroll
    for (int ii = 0; ii < 16; ii++) {
        int r = ii * 4 + ty;
        tile[r][tx] = (float)vin[((long)(b * SEQ + st * 64 + r)) * DIMN + ct * 64 + tx];
    }
    __syncthreads();
#pragma unroll
    for (int ii = 0; ii < 16; ii++) {
        int c = ii * 4 + ty;
        vt[((long)(b * DIMN + ct * 64 + c)) * SEQ + st * 64 + tx] = (bf16)tile[tx][c];
    }
}

// -------- flash-style attention, S^T formulation.
// QK^T computed transposed (A=K,B=Q) so lane's 4 C-values are contiguous along kr
// -> P stored to LDS with b64 writes; L-reduce is 2 shfls. K/V staged via
// global_load_lds with seg-XOR swizzle. No max-subtraction (scores O(+-5)).
__global__ __launch_bounds__(256, 2) void attention(
    const bf16* __restrict__ Q, const bf16* __restrict__ Kb,
    const bf16* __restrict__ Vt, bf16* __restrict__ O)
{
    __shared__ __attribute__((aligned(16))) bf16 Ksh[64 * 128];    // [kr][d], seg^=(kr&15)
    __shared__ __attribute__((aligned(16))) bf16 Vsh[128 * 64];    // [d][kr], seg^=(d&7)
    __shared__ __attribute__((aligned(16))) bf16 Psh[4][32 * 72];  // per-wave P[m][kr], pad 72
    __shared__ float Lsh[4][32];

    const int t = threadIdx.x;
    const int lane = t & 63, wave = t >> 6;
    const int l15 = lane & 15, quad = lane >> 4;
    const int bh = blockIdx.y, b = bh >> 4, h = bh & 15;
    const int qt = blockIdx.x;
    const long qrow0 = (long)b * SEQ + qt * 128 + wave * 32;
    const bf16* qbase = Q  + qrow0 * DIMN + h * HD;
    const bf16* kbase = Kb + (long)b * SEQ * DIMN + h * HD;
    const bf16* vbase = Vt + (long)bh * HD * SEQ;

    // Q fragments in registers (pre-scaled by rmsnorm_rope): A/B[m=l15][k=quad*8+j]
    bf16x8 qf[2][4];
#pragma unroll
    for (int im = 0; im < 2; im++)
#pragma unroll
        for (int kd = 0; kd < 4; kd++)
            qf[im][kd] = *(const bf16x8*)(qbase + (long)(im * 16 + l15) * DIMN + kd * 32 + quad * 8);

    // staging pointers (4 passes each for K: 64x16 segs, V: 128x8 segs)
    const bf16* kgp[4]; const bf16* vgp[4]; bf16* ksd[4]; bf16* vsd[4];
#pragma unroll
    for (int it = 0; it < 4; it++) {
        int fs = it * 256 + t;
        int kr = fs >> 4, kp = fs & 15, kks = kp ^ (kr & 15);
        kgp[it] = kbase + (long)kr * DIMN + kks * 8;
        ksd[it] = Ksh + fs * 8;
        int dr = fs >> 3, vp = fs & 7, vks = vp ^ (dr & 7);
        vgp[it] = vbase + (long)dr * SEQ + vks * 8;
        vsd[it] = Vsh + fs * 8;
    }

    f32x4 o_acc[2][8] = {};
    float Lt[2] = {0.f, 0.f};

    for (int kt = 0; kt < 32; kt++) {
#pragma unroll
        for (int it = 0; it < 4; it++) {
            gld_lds16(kgp[it] + (long)(kt * 64) * DIMN, ksd[it]);
            gld_lds16(vgp[it] + kt * 64, vsd[it]);
        }
        __syncthreads();

        // ---- S^T = K Q^T : D[kr][m] tiles st[jk][im] ----
        f32x4 st[4][2] = {};
#pragma unroll
        for (int jk = 0; jk < 4; jk++)
#pragma unroll
            for (int kd = 0; kd < 4; kd++) {
                bf16x8 kf = *(const bf16x8*)(Ksh + (jk * 16 + l15) * 128 + (((kd * 4 + quad) ^ l15) & 15) * 8);
                st[jk][0] = __builtin_amdgcn_mfma_f32_16x16x32_bf16(kf, qf[0][kd], st[jk][0], 0, 0, 0);
                st[jk][1] = __builtin_amdgcn_mfma_f32_16x16x32_bf16(kf, qf[1][kd], st[jk][1], 0, 0, 0);
            }

        // ---- exp + P->LDS (b64 stores, C-layout rows are contiguous kr) + L ----
#pragma unroll
        for (int im = 0; im < 2; im++) {
            float part = 0.f;
#pragma unroll
            for (int jk = 0; jk < 4; jk++) {
                bf16x4 pk;
#pragma unroll
                for (int r = 0; r < 4; r++) {
                    float e = __expf(st[jk][im][r]);
                    part += e;
                    pk[r] = (bf16)e;
                }
                *(bf16x4*)(Psh[wave] + (im * 16 + l15) * 72 + jk * 16 + quad * 4) = pk;
            }
            part += __shfl_xor(part, 16, 64);
            part += __shfl_xor(part, 32, 64);
            Lt[im] += part;
        }
        // no barrier: Psh[wave] is wave-private, LDS ops in-order per wave

        // ---- O += P V ----
#pragma unroll
        for (int kd2 = 0; kd2 < 2; kd2++) {
            bf16x8 pa[2];
            pa[0] = *(const bf16x8*)(Psh[wave] + (l15)      * 72 + kd2 * 32 + quad * 8);
            pa[1] = *(const bf16x8*)(Psh[wave] + (16 + l15) * 72 + kd2 * 32 + quad * 8);
#pragma unroll
            for (int dj = 0; dj < 8; dj++) {
                bf16x8 vfr = *(const bf16x8*)(Vsh + (dj * 16 + l15) * 64 + (((kd2 * 4 + quad) ^ l15) & 7) * 8);
                o_acc[0][dj] = __builtin_amdgcn_mfma_f32_16x16x32_bf16(pa[0], vfr, o_acc[0][dj], 0, 0, 0);
                o_acc[1][dj] = __builtin_amdgcn_mfma_f32_16x16x32_bf16(pa[1], vfr, o_acc[1][dj], 0, 0, 0);
            }
        }
        __syncthreads();
    }

    // L lives at lane l15 (m = im*16+l15); broadcast via LDS for the C-layout store
    if (quad == 0) { Lsh[wave][l15] = Lt[0]; Lsh[wave][16 + l15] = Lt[1]; }
    __syncthreads();

#pragma unroll
    for (int i = 0; i < 2; i++)
#pragma unroll
        for (int r = 0; r < 4; r++) {
            float inv = 1.0f / Lsh[wave][i * 16 + quad * 4 + r];
            long orow = qrow0 + i * 16 + quad * 4 + r;
#pragma unroll
            for (int dj = 0; dj < 8; dj++)
                O[orow * DIMN + h * HD + dj * 16 + l15] = (bf16)(o_acc[i][dj][r] * inv);
        }
}

extern "C" void kernel_launch(void* const* d_in, const int* in_sizes, int n_in,
                              void* d_out, int out_size, void* d_ws, size_t ws_size,
                              hipStream_t stream) {
    const float* x     = (const float*)d_in[0];
    const float* freqs = (const float*)d_in[1];
    const float* wq    = (const float*)d_in[2];
    const float* bq    = (const float*)d_in[3];
    const float* wk    = (const float*)d_in[4];
    const float* bk    = (const float*)d_in[5];
    const float* wv    = (const float*)d_in[6];
    const float* bv    = (const float*)d_in[7];
    const float* wo    = (const float*)d_in[8];
    const float* bo    = (const float*)d_in[9];
    const float* gq    = (const float*)d_in[10];
    const float* gk    = (const float*)d_in[11];
    float* out = (float*)d_out;

    const size_t MAT  = (size_t)4096 * 2048 * 2;   // 16 MiB (bf16 activations)
    const size_t WMAT = (size_t)2048 * 2048 * 2;   // 8 MiB  (bf16 weights)
    char* p = (char*)d_ws;
    bf16* xb  = (bf16*)p; p += MAT;
    bf16* wqb = (bf16*)p; p += WMAT;
    bf16* wkb = (bf16*)p; p += WMAT;
    bf16* wvb = (bf16*)p; p += WMAT;
    bf16* wob = (bf16*)p; p += WMAT;
    bf16* qb  = (bf16*)p; p += MAT;
    bf16* kb  = (bf16*)p; p += MAT;
    bf16* vb  = (bf16*)p; p += MAT;
    bf16* vt  = (bf16*)p; p += MAT;
    bf16* attn = qb;   // alias (safe: each attn block writes only rows/cols it alone read)

    cast_f32_bf16<<<8192, 256, 0, stream>>>(x, xb, 2097152);
    cast_w4<<<dim3(4096, 4), 256, 0, stream>>>(wq, wk, wv, wo, wqb, wkb, wvb, wob, 1048576);

    gemm_bt<0><<<dim3(16, 32, 3), 256, 0, stream>>>(xb, wqb, wkb, wvb,
                                                    bq, bk, bv, qb, kb, vb);
    rmsnorm_rope<<<dim3(4096, 2), 256, 0, stream>>>(qb, kb, gq, gk, freqs);
    transpose_v<<<dim3(32, 32, 2), 256, 0, stream>>>(vb, vt);
    attention<<<dim3(16, 32), 256, 0, stream>>>(qb, kb, vt, attn);
    gemm_bt<1><<<dim3(16, 32, 1), 256, 0, stream>>>(attn, wob, wob, wob,
                                                    bo, bo, bo, out, out, out);
}